// Round 8
// baseline (742.741 us; speedup 1.0000x reference)
//
#include <hip/hip_runtime.h>
#include <hip/hip_bf16.h>
#include <stdint.h>

#define NN 8192      // nodes
#define NE 16384     // hyperedges
#define RCAP 128     // max row degree bucket (Poisson lambda~67)
#define CCAP 96      // max col degree bucket (Poisson lambda~34)
#define NGEMM (NN/4) // y0-gemm blocks, placed at the FRONT of the scan grid

typedef float f32x4 __attribute__((ext_vector_type(4)));

// ---------------- workspace layout (bytes) ----------------
#define OFF_COLCNT   0u
#define MEMSET_BYTES (NE*4u)                           // only col_cnt needs zeroing
#define OFF_ROWCNT   MEMSET_BYTES
#define OFF_RSCALE   (OFF_ROWCNT + NN*4u)
#define OFF_CSR      (OFF_RSCALE + NN*4u)              // [NN][RCAP] u32 = 4 MB
#define OFF_CSC      (OFF_CSR + NN*RCAP*4u)            // [NE][CCAP] u32 = 6 MB
#define OFF_Y0       (OFF_CSC + NE*CCAP*4u)            // [NN][64] f32 (scaled in place)
#define OFF_Z1       (OFF_Y0 + NN*64*4u)               // [NE][64] f32, pre-scaled by colscale

// K_A: blocks 0..NGEMM-1 compute y0 = x0 @ W0 (unscaled; rides free under BW).
// Blocks NGEMM.. scan one B1 row each, two-phase (LDS-only during the stream,
// batched global atomics after), with an explicit 2-deep load pipeline and
// ballot-gated hit handling so the stream keeps >=1 load in flight.
__global__ __launch_bounds__(256) void k_scan_gemm(const float* __restrict__ B1,
        const float* __restrict__ x0, const float* __restrict__ W0,
        uint32_t* __restrict__ row_cnt, uint32_t* __restrict__ col_cnt,
        uint32_t* __restrict__ csr_col, uint32_t* __restrict__ csc_row,
        float* __restrict__ y0) {
    __shared__ float wsm[64 * 64];
    __shared__ float xs[4][64];
    __shared__ uint32_t hits[RCAP];
    __shared__ uint32_t rcur;
    const int tid = threadIdx.x;
    if (blockIdx.x >= NGEMM) {
        const int i = blockIdx.x - NGEMM;
        if (tid == 0) rcur = 0;
        __syncthreads();
        const float* rowp = B1 + (long long)i * NE;
        // 2-deep pipeline: next line issued before current line's checks.
        f32x4 cur = *reinterpret_cast<const f32x4*>(rowp + tid * 4);
        for (int it = 0; it < 16; ++it) {
            f32x4 nxt = cur;
            if (it < 15)
                nxt = *reinterpret_cast<const f32x4*>(rowp + (it + 1) * 1024 + tid * 4);
            int local = it * 1024 + tid * 4;
            #pragma unroll
            for (int q = 0; q < 4; ++q) {
                // scalar-branch skip for the (common) all-zero wave case
                if (__ballot(cur[q] != 0.0f) != 0ull) {
                    if (cur[q] != 0.0f) {
                        uint32_t p = atomicAdd(&rcur, 1u);   // LDS atomic only
                        if (p < RCAP) hits[p] = (uint32_t)(local + q);
                    }
                }
            }
            cur = nxt;
        }
        __syncthreads();
        uint32_t cnt = rcur;
        uint32_t cl = cnt > RCAP ? RCAP : cnt;
        if ((uint32_t)tid < cl) {
            uint32_t j = hits[tid];
            csr_col[(uint32_t)i * RCAP + tid] = j;
            uint32_t qq = atomicAdd(&col_cnt[j], 1u);        // one batched drain per row
            if (qq < CCAP) csc_row[j * CCAP + qq] = (uint32_t)i;
        }
        if (tid == 0) row_cnt[i] = cnt;            // true count (clamp at use sites)
    } else {
        int c = tid & 63, rr = tid >> 6;
        for (int k = tid * 4; k < 4096; k += 1024)
            *reinterpret_cast<f32x4*>(wsm + k) =
                *reinterpret_cast<const f32x4*>(W0 + k);
        int row0 = blockIdx.x * 4;
        xs[rr][c] = x0[(row0 + rr) * 64 + c];
        __syncthreads();
        float acc = 0.f;
        #pragma unroll
        for (int k = 0; k < 64; ++k) acc = fmaf(xs[rr][k], wsm[k * 64 + c], acc);
        y0[(row0 + rr) * 64 + c] = acc;
    }
}

// K_B: one wave per node row. rscale[i] = nnorm[i]/sum_{j in row} enorm[j];
// scales y0 row in place so the edge gather is a pure sum.
__global__ __launch_bounds__(256) void k_rowscale(
        const uint32_t* __restrict__ row_cnt, const uint32_t* __restrict__ col_cnt,
        const uint32_t* __restrict__ csr_col,
        float* __restrict__ rowscale, float* __restrict__ y0) {
    int i = blockIdx.x * 4 + (threadIdx.x >> 6);
    int lane = threadIdx.x & 63;
    uint32_t c = row_cnt[i];
    uint32_t cl = c > RCAP ? RCAP : c;
    const uint32_t* p = csr_col + (uint32_t)i * RCAP;
    float s = 0.f;
    for (uint32_t t = lane; t < cl; t += 64) {
        float cj = (float)col_cnt[p[t]];
        s += 1.0f / (cj * sqrtf(cj));
    }
    #pragma unroll
    for (int off = 32; off >= 1; off >>= 1) s += __shfl_xor(s, off);
    float rs = 1.0f / (sqrtf((float)c) * s);
    y0[i * 64 + lane] *= rs;
    if (lane == 0) rowscale[i] = rs;
}

// K_C: per edge j (4/block): gather x1row = sum_{i in col j} y0s[i,:] with
// prefetched indices (u0/u1) + wave-uniform trip count. On-the-fly colscale
// (fl==0 lanes accumulate 1/sqrt(row_cnt)), relu->out1, then block 64x64 GEMM:
// z1s = colscale*(x1@W1).
__global__ __launch_bounds__(256) void k_edge_fused(
        const uint32_t* __restrict__ col_cnt, const uint32_t* __restrict__ csc_row,
        const uint32_t* __restrict__ row_cnt, const float* __restrict__ y0s,
        const float* __restrict__ bias01, const float* __restrict__ W1,
        float* __restrict__ z1s, float* __restrict__ out1) {
    __shared__ float w1s[64 * 64];
    __shared__ float xrow[4][64];
    __shared__ float csh[4];
    int tid = threadIdx.x;
    for (int k = tid * 4; k < 4096; k += 1024)
        *reinterpret_cast<f32x4*>(w1s + k) =
            *reinterpret_cast<const f32x4*>(W1 + k);
    int w = tid >> 6, lane = tid & 63;
    int j = blockIdx.x * 4 + w;
    uint32_t c = col_cnt[j];
    uint32_t e = c > CCAP ? CCAP : c;
    const uint32_t* p = csc_row + (uint32_t)j * CCAP;
    uint32_t u0 = p[lane];                               // indices 0..63
    uint32_t u1 = (e > 64u) ? p[64 + lane] : 0u;         // wave-uniform skip
    int g = lane >> 4, fl = lane & 15;
    float4 acc = make_float4(0.f, 0.f, 0.f, 0.f);
    float ns = 0.f;
    uint32_t niter = (e + 3u) >> 2;         // uniform across the wave
    for (uint32_t k = 0; k < niter; ++k) {
        uint32_t t = g + 4u * k;
        uint32_t idx = (t < 64u) ? (uint32_t)__shfl((int)u0, (int)t)
                                 : (uint32_t)__shfl((int)u1, (int)(t - 64u));
        if (t < e) {
            const float4 v = *reinterpret_cast<const float4*>(y0s + idx * 64u + fl * 4);
            if (fl == 0) ns += 1.0f / sqrtf((float)row_cnt[idx]);
            acc.x += v.x; acc.y += v.y; acc.z += v.z; acc.w += v.w;
        }
    }
    acc.x += __shfl_xor(acc.x, 16); acc.y += __shfl_xor(acc.y, 16);
    acc.z += __shfl_xor(acc.z, 16); acc.w += __shfl_xor(acc.w, 16);
    acc.x += __shfl_xor(acc.x, 32); acc.y += __shfl_xor(acc.y, 32);
    acc.z += __shfl_xor(acc.z, 32); acc.w += __shfl_xor(acc.w, 32);
    ns += __shfl_xor(ns, 16); ns += __shfl_xor(ns, 32);
    float cf = (float)c;
    float cs = __shfl(1.0f / (cf * sqrtf(cf) * ns), 0);   // colscale[j], broadcast
    if (g == 0) {
        const float4 bb = *reinterpret_cast<const float4*>(bias01 + fl * 4);
        float4 val = make_float4(fmaf(cs, acc.x, bb.x), fmaf(cs, acc.y, bb.y),
                                 fmaf(cs, acc.z, bb.z), fmaf(cs, acc.w, bb.w));
        *reinterpret_cast<float4*>(&xrow[w][fl * 4]) = val;
        float4 r = make_float4(fmaxf(val.x, 0.f), fmaxf(val.y, 0.f),
                               fmaxf(val.z, 0.f), fmaxf(val.w, 0.f));
        *reinterpret_cast<float4*>(out1 + j * 64u + fl * 4) = r;
        if (fl == 0) csh[w] = cs;
    }
    __syncthreads();
    float z = 0.f;
    #pragma unroll
    for (int k = 0; k < 64; ++k) z = fmaf(xrow[w][k], w1s[k * 64 + lane], z);
    z1s[j * 64 + lane] = csh[w] * z;
}

// K_D: out0[i,:] = relu(rowscale[i] * sum_{j in row i} z1s[j,:] + b10)
__global__ __launch_bounds__(256) void k_node_gather(
        const uint32_t* __restrict__ row_cnt, const uint32_t* __restrict__ csr_col,
        const float* __restrict__ rowscale, const float* __restrict__ z1s,
        const float* __restrict__ bias10, float* __restrict__ out0) {
    int w = threadIdx.x >> 6, lane = threadIdx.x & 63;
    int i = blockIdx.x * 4 + w;
    uint32_t c = row_cnt[i];
    uint32_t e = c > RCAP ? RCAP : c;
    const uint32_t* p = csr_col + (uint32_t)i * RCAP;
    uint32_t u0 = p[lane];
    uint32_t u1 = (e > 64u) ? p[64 + lane] : 0u;         // wave-uniform skip
    int g = lane >> 4, fl = lane & 15;
    float4 acc = make_float4(0.f, 0.f, 0.f, 0.f);
    uint32_t niter = (e + 3u) >> 2;         // uniform across the wave
    for (uint32_t k = 0; k < niter; ++k) {
        uint32_t t = g + 4u * k;
        uint32_t idx = (t < 64u) ? (uint32_t)__shfl((int)u0, (int)t)
                                 : (uint32_t)__shfl((int)u1, (int)(t - 64u));
        if (t < e) {
            const float4 v = *reinterpret_cast<const float4*>(z1s + idx * 64u + fl * 4);
            acc.x += v.x; acc.y += v.y; acc.z += v.z; acc.w += v.w;
        }
    }
    acc.x += __shfl_xor(acc.x, 16); acc.y += __shfl_xor(acc.y, 16);
    acc.z += __shfl_xor(acc.z, 16); acc.w += __shfl_xor(acc.w, 16);
    acc.x += __shfl_xor(acc.x, 32); acc.y += __shfl_xor(acc.y, 32);
    acc.z += __shfl_xor(acc.z, 32); acc.w += __shfl_xor(acc.w, 32);
    if (g == 0) {
        float rs = rowscale[i];
        const float4 bb = *reinterpret_cast<const float4*>(bias10 + fl * 4);
        float4 r = make_float4(fmaxf(fmaf(rs, acc.x, bb.x), 0.f),
                               fmaxf(fmaf(rs, acc.y, bb.y), 0.f),
                               fmaxf(fmaf(rs, acc.z, bb.z), 0.f),
                               fmaxf(fmaf(rs, acc.w, bb.w), 0.f));
        *reinterpret_cast<float4*>(out0 + i * 64u + fl * 4) = r;
    }
}

extern "C" void kernel_launch(void* const* d_in, const int* in_sizes, int n_in,
                              void* d_out, int out_size, void* d_ws, size_t ws_size,
                              hipStream_t stream) {
    const float* x0  = (const float*)d_in[0];
    const float* B1  = (const float*)d_in[1];
    const float* W0  = (const float*)d_in[2];
    const float* W1  = (const float*)d_in[3];
    const float* b01 = (const float*)d_in[4];
    const float* b10 = (const float*)d_in[5];
    float* out = (float*)d_out;
    char* ws = (char*)d_ws;

    uint32_t* col_cnt = (uint32_t*)(ws + OFF_COLCNT);
    uint32_t* row_cnt = (uint32_t*)(ws + OFF_ROWCNT);
    float*    rscale  = (float*)(ws + OFF_RSCALE);
    uint32_t* csr_col = (uint32_t*)(ws + OFF_CSR);
    uint32_t* csc_row = (uint32_t*)(ws + OFF_CSC);
    float*    y0      = (float*)(ws + OFF_Y0);
    float*    z1      = (float*)(ws + OFF_Z1);

    hipMemsetAsync(col_cnt, 0, MEMSET_BYTES, stream);

    k_scan_gemm<<<NN + NGEMM, 256, 0, stream>>>(B1, x0, W0, row_cnt, col_cnt,
            csr_col, csc_row, y0);
    k_rowscale<<<NN / 4, 256, 0, stream>>>(row_cnt, col_cnt, csr_col, rscale, y0);
    k_edge_fused<<<NE / 4, 256, 0, stream>>>(col_cnt, csc_row, row_cnt, y0,
            b01, W1, z1, out + NN * 64);
    k_node_gather<<<NN / 4, 256, 0, stream>>>(row_cnt, csr_col, rscale, z1, b10, out);
}

// Round 9
// 742.477 us; speedup vs baseline: 1.0004x; 1.0004x over previous
//
#include <hip/hip_runtime.h>
#include <hip/hip_bf16.h>
#include <stdint.h>

#define NN 8192      // nodes
#define NE 16384     // hyperedges
#define RCAP 128     // max row degree bucket (Poisson lambda~67)
#define CCAP 96      // max col degree bucket (Poisson lambda~34)
#define NGEMM (NN/4) // y0-gemm blocks, placed at the FRONT of the grid

typedef float f32x4 __attribute__((ext_vector_type(4)));

// ---------------- workspace layout (bytes) ----------------
#define OFF_COLCNT   0u
#define MEMSET_BYTES (NE*4u)                           // only col_cnt needs zeroing
#define OFF_ROWCNT   MEMSET_BYTES
#define OFF_RSCALE   (OFF_ROWCNT + NN*4u)
#define OFF_CSR      (OFF_RSCALE + NN*4u)              // [NN][RCAP] u32 = 4 MB
#define OFF_CSC      (OFF_CSR + NN*RCAP*4u)            // [NE][CCAP] u32 = 6 MB
#define OFF_Y0       (OFF_CSC + NE*CCAP*4u)            // [NN][64] f32 (scaled in place)
#define OFF_Z1       (OFF_Y0 + NN*64*4u)               // [NE][64] f32, pre-scaled by colscale

// K_A: blocks 0..NGEMM-1 compute y0 = x0 @ W0 (rides free under the B1 stream).
// Blocks NGEMM.. scan one B1 row each, two-phase: (A) stream the row with ONLY
// LDS side effects (keeps the vmcnt load pipe free of atomic-return drains),
// hits -> LDS list; (B) lanes tid<cnt each emit one nonzero: csr store + one
// batched global atomic + csc scatter. Simple per-lane branch — R8's explicit
// pipeline/ballot variant regressed 20us; the compiler schedules this better.
__global__ __launch_bounds__(256) void k_scan_gemm(const float* __restrict__ B1,
        const float* __restrict__ x0, const float* __restrict__ W0,
        uint32_t* __restrict__ row_cnt, uint32_t* __restrict__ col_cnt,
        uint32_t* __restrict__ csr_col, uint32_t* __restrict__ csc_row,
        float* __restrict__ y0) {
    __shared__ float wsm[64 * 64];
    __shared__ float xs[4][64];
    __shared__ uint32_t hits[RCAP];
    __shared__ uint32_t rcur;
    const int tid = threadIdx.x;
    if (blockIdx.x >= NGEMM) {
        const int i = blockIdx.x - NGEMM;
        if (tid == 0) rcur = 0;
        __syncthreads();
        const long long base = (long long)i * NE;
        for (int it = 0; it < 16; ++it) {
            int local = it * 1024 + tid * 4;        // 0..16383
            f32x4 v = *reinterpret_cast<const f32x4*>(B1 + base + local);
            #pragma unroll
            for (int q = 0; q < 4; ++q) {
                if (v[q] != 0.0f) {
                    uint32_t p = atomicAdd(&rcur, 1u);       // LDS atomic only
                    if (p < RCAP) hits[p] = (uint32_t)(local + q);
                }
            }
        }
        __syncthreads();
        uint32_t cnt = rcur;
        uint32_t cl = cnt > RCAP ? RCAP : cnt;
        if ((uint32_t)tid < cl) {
            uint32_t j = hits[tid];
            csr_col[(uint32_t)i * RCAP + tid] = j;
            uint32_t qq = atomicAdd(&col_cnt[j], 1u);        // one batched drain per row
            if (qq < CCAP) csc_row[j * CCAP + qq] = (uint32_t)i;
        }
        if (tid == 0) row_cnt[i] = cnt;            // true count (clamp at use sites)
    } else {
        int c = tid & 63, rr = tid >> 6;
        for (int k = tid * 4; k < 4096; k += 1024)
            *reinterpret_cast<f32x4*>(wsm + k) =
                *reinterpret_cast<const f32x4*>(W0 + k);
        int row0 = blockIdx.x * 4;
        xs[rr][c] = x0[(row0 + rr) * 64 + c];
        __syncthreads();
        float acc = 0.f;
        #pragma unroll
        for (int k = 0; k < 64; ++k) acc = fmaf(xs[rr][k], wsm[k * 64 + c], acc);
        y0[(row0 + rr) * 64 + c] = acc;
    }
}

// K_B: one wave per node row. rscale[i] = nnorm[i]/sum_{j in row} enorm[j];
// scales y0 row in place so the edge gather is a pure sum.
__global__ __launch_bounds__(256) void k_rowscale(
        const uint32_t* __restrict__ row_cnt, const uint32_t* __restrict__ col_cnt,
        const uint32_t* __restrict__ csr_col,
        float* __restrict__ rowscale, float* __restrict__ y0) {
    int i = blockIdx.x * 4 + (threadIdx.x >> 6);
    int lane = threadIdx.x & 63;
    uint32_t c = row_cnt[i];
    uint32_t cl = c > RCAP ? RCAP : c;
    const uint32_t* p = csr_col + (uint32_t)i * RCAP;
    float s = 0.f;
    for (uint32_t t = lane; t < cl; t += 64) {
        float cj = (float)col_cnt[p[t]];
        s += 1.0f / (cj * sqrtf(cj));
    }
    #pragma unroll
    for (int off = 32; off >= 1; off >>= 1) s += __shfl_xor(s, off);
    float rs = 1.0f / (sqrtf((float)c) * s);
    y0[i * 64 + lane] *= rs;
    if (lane == 0) rowscale[i] = rs;
}

// K_C: per edge j (4/block): gather x1row = sum_{i in col j} y0s[i,:] with
// prefetched indices (u0/u1) + wave-uniform trip count. On-the-fly colscale
// (fl==0 lanes accumulate 1/sqrt(row_cnt)), relu->out1, then block 64x64 GEMM:
// z1s = colscale*(x1@W1).
__global__ __launch_bounds__(256) void k_edge_fused(
        const uint32_t* __restrict__ col_cnt, const uint32_t* __restrict__ csc_row,
        const uint32_t* __restrict__ row_cnt, const float* __restrict__ y0s,
        const float* __restrict__ bias01, const float* __restrict__ W1,
        float* __restrict__ z1s, float* __restrict__ out1) {
    __shared__ float w1s[64 * 64];
    __shared__ float xrow[4][64];
    __shared__ float csh[4];
    int tid = threadIdx.x;
    for (int k = tid * 4; k < 4096; k += 1024)
        *reinterpret_cast<f32x4*>(w1s + k) =
            *reinterpret_cast<const f32x4*>(W1 + k);
    int w = tid >> 6, lane = tid & 63;
    int j = blockIdx.x * 4 + w;
    uint32_t c = col_cnt[j];
    uint32_t e = c > CCAP ? CCAP : c;
    const uint32_t* p = csc_row + (uint32_t)j * CCAP;
    uint32_t u0 = p[lane];                               // indices 0..63
    uint32_t u1 = (e > 64u) ? p[64 + lane] : 0u;         // wave-uniform skip
    int g = lane >> 4, fl = lane & 15;
    float4 acc = make_float4(0.f, 0.f, 0.f, 0.f);
    float ns = 0.f;
    uint32_t niter = (e + 3u) >> 2;         // uniform across the wave
    for (uint32_t k = 0; k < niter; ++k) {
        uint32_t t = g + 4u * k;
        uint32_t idx = (t < 64u) ? (uint32_t)__shfl((int)u0, (int)t)
                                 : (uint32_t)__shfl((int)u1, (int)(t - 64u));
        if (t < e) {
            const float4 v = *reinterpret_cast<const float4*>(y0s + idx * 64u + fl * 4);
            if (fl == 0) ns += 1.0f / sqrtf((float)row_cnt[idx]);
            acc.x += v.x; acc.y += v.y; acc.z += v.z; acc.w += v.w;
        }
    }
    acc.x += __shfl_xor(acc.x, 16); acc.y += __shfl_xor(acc.y, 16);
    acc.z += __shfl_xor(acc.z, 16); acc.w += __shfl_xor(acc.w, 16);
    acc.x += __shfl_xor(acc.x, 32); acc.y += __shfl_xor(acc.y, 32);
    acc.z += __shfl_xor(acc.z, 32); acc.w += __shfl_xor(acc.w, 32);
    ns += __shfl_xor(ns, 16); ns += __shfl_xor(ns, 32);
    float cf = (float)c;
    float cs = __shfl(1.0f / (cf * sqrtf(cf) * ns), 0);   // colscale[j], broadcast
    if (g == 0) {
        const float4 bb = *reinterpret_cast<const float4*>(bias01 + fl * 4);
        float4 val = make_float4(fmaf(cs, acc.x, bb.x), fmaf(cs, acc.y, bb.y),
                                 fmaf(cs, acc.z, bb.z), fmaf(cs, acc.w, bb.w));
        *reinterpret_cast<float4*>(&xrow[w][fl * 4]) = val;
        float4 r = make_float4(fmaxf(val.x, 0.f), fmaxf(val.y, 0.f),
                               fmaxf(val.z, 0.f), fmaxf(val.w, 0.f));
        *reinterpret_cast<float4*>(out1 + j * 64u + fl * 4) = r;
        if (fl == 0) csh[w] = cs;
    }
    __syncthreads();
    float z = 0.f;
    #pragma unroll
    for (int k = 0; k < 64; ++k) z = fmaf(xrow[w][k], w1s[k * 64 + lane], z);
    z1s[j * 64 + lane] = csh[w] * z;
}

// K_D: out0[i,:] = relu(rowscale[i] * sum_{j in row i} z1s[j,:] + b10)
__global__ __launch_bounds__(256) void k_node_gather(
        const uint32_t* __restrict__ row_cnt, const uint32_t* __restrict__ csr_col,
        const float* __restrict__ rowscale, const float* __restrict__ z1s,
        const float* __restrict__ bias10, float* __restrict__ out0) {
    int w = threadIdx.x >> 6, lane = threadIdx.x & 63;
    int i = blockIdx.x * 4 + w;
    uint32_t c = row_cnt[i];
    uint32_t e = c > RCAP ? RCAP : c;
    const uint32_t* p = csr_col + (uint32_t)i * RCAP;
    uint32_t u0 = p[lane];
    uint32_t u1 = (e > 64u) ? p[64 + lane] : 0u;         // wave-uniform skip
    int g = lane >> 4, fl = lane & 15;
    float4 acc = make_float4(0.f, 0.f, 0.f, 0.f);
    uint32_t niter = (e + 3u) >> 2;         // uniform across the wave
    for (uint32_t k = 0; k < niter; ++k) {
        uint32_t t = g + 4u * k;
        uint32_t idx = (t < 64u) ? (uint32_t)__shfl((int)u0, (int)t)
                                 : (uint32_t)__shfl((int)u1, (int)(t - 64u));
        if (t < e) {
            const float4 v = *reinterpret_cast<const float4*>(z1s + idx * 64u + fl * 4);
            acc.x += v.x; acc.y += v.y; acc.z += v.z; acc.w += v.w;
        }
    }
    acc.x += __shfl_xor(acc.x, 16); acc.y += __shfl_xor(acc.y, 16);
    acc.z += __shfl_xor(acc.z, 16); acc.w += __shfl_xor(acc.w, 16);
    acc.x += __shfl_xor(acc.x, 32); acc.y += __shfl_xor(acc.y, 32);
    acc.z += __shfl_xor(acc.z, 32); acc.w += __shfl_xor(acc.w, 32);
    if (g == 0) {
        float rs = rowscale[i];
        const float4 bb = *reinterpret_cast<const float4*>(bias10 + fl * 4);
        float4 r = make_float4(fmaxf(fmaf(rs, acc.x, bb.x), 0.f),
                               fmaxf(fmaf(rs, acc.y, bb.y), 0.f),
                               fmaxf(fmaf(rs, acc.z, bb.z), 0.f),
                               fmaxf(fmaf(rs, acc.w, bb.w), 0.f));
        *reinterpret_cast<float4*>(out0 + i * 64u + fl * 4) = r;
    }
}

extern "C" void kernel_launch(void* const* d_in, const int* in_sizes, int n_in,
                              void* d_out, int out_size, void* d_ws, size_t ws_size,
                              hipStream_t stream) {
    const float* x0  = (const float*)d_in[0];
    const float* B1  = (const float*)d_in[1];
    const float* W0  = (const float*)d_in[2];
    const float* W1  = (const float*)d_in[3];
    const float* b01 = (const float*)d_in[4];
    const float* b10 = (const float*)d_in[5];
    float* out = (float*)d_out;
    char* ws = (char*)d_ws;

    uint32_t* col_cnt = (uint32_t*)(ws + OFF_COLCNT);
    uint32_t* row_cnt = (uint32_t*)(ws + OFF_ROWCNT);
    float*    rscale  = (float*)(ws + OFF_RSCALE);
    uint32_t* csr_col = (uint32_t*)(ws + OFF_CSR);
    uint32_t* csc_row = (uint32_t*)(ws + OFF_CSC);
    float*    y0      = (float*)(ws + OFF_Y0);
    float*    z1      = (float*)(ws + OFF_Z1);

    hipMemsetAsync(col_cnt, 0, MEMSET_BYTES, stream);

    k_scan_gemm<<<NN + NGEMM, 256, 0, stream>>>(B1, x0, W0, row_cnt, col_cnt,
            csr_col, csc_row, y0);
    k_rowscale<<<NN / 4, 256, 0, stream>>>(row_cnt, col_cnt, csr_col, rscale, y0);
    k_edge_fused<<<NE / 4, 256, 0, stream>>>(col_cnt, csc_row, row_cnt, y0,
            b01, W1, z1, out + NN * 64);
    k_node_gather<<<NN / 4, 256, 0, stream>>>(row_cnt, csr_col, rscale, z1, b10, out);
}

// Round 10
// 735.847 us; speedup vs baseline: 1.0094x; 1.0090x over previous
//
#include <hip/hip_runtime.h>
#include <hip/hip_bf16.h>
#include <stdint.h>

#define NN 8192      // nodes
#define NE 16384     // hyperedges
#define RCAP 128     // max row degree bucket (Poisson lambda~67)
#define CCAP 96      // max col degree bucket (Poisson lambda~34)

typedef float f32x4 __attribute__((ext_vector_type(4)));

// ---------------- workspace layout (bytes) ----------------
#define OFF_COLCNT   0u
#define MEMSET_BYTES (NE*4u)                           // only col_cnt needs zeroing
#define OFF_ROWCNT   MEMSET_BYTES
#define OFF_RSCALE   (OFF_ROWCNT + NN*4u)
#define OFF_CSR      (OFF_RSCALE + NN*4u)              // [NN][RCAP] u32 = 4 MB
#define OFF_CSC      (OFF_CSR + NN*RCAP*4u)            // [NE][CCAP] u32 = 6 MB
#define OFF_Y0       (OFF_CSC + NE*CCAP*4u)            // [NN][64] f32 (scaled in place)
#define OFF_Z1       (OFF_Y0 + NN*64*4u)               // [NE][64] f32, pre-scaled by colscale

// K_A: blocks 0..NN-1 scan one B1 row each (dispatched FIRST so the B1 stream
// starts immediately); blocks NN.. compute y0 = x0 @ W0, riding the scan's
// drain tail. Two-phase scan: (A) stream the row with ONLY LDS side effects
// (keeps the vmcnt load pipe free of atomic-return drains), hits -> LDS list;
// (B) lanes tid<cnt each emit one nonzero: csr store + one batched global
// atomic + csc scatter. Grid order matters: gemm-at-front (R8/R9) cost ~20us.
__global__ __launch_bounds__(256) void k_scan_gemm(const float* __restrict__ B1,
        const float* __restrict__ x0, const float* __restrict__ W0,
        uint32_t* __restrict__ row_cnt, uint32_t* __restrict__ col_cnt,
        uint32_t* __restrict__ csr_col, uint32_t* __restrict__ csc_row,
        float* __restrict__ y0) {
    __shared__ float wsm[64 * 64];
    __shared__ float xs[4][64];
    __shared__ uint32_t hits[RCAP];
    __shared__ uint32_t rcur;
    const int tid = threadIdx.x;
    if (blockIdx.x < NN) {
        const int i = blockIdx.x;
        if (tid == 0) rcur = 0;
        __syncthreads();
        const long long base = (long long)i * NE;
        for (int it = 0; it < 16; ++it) {
            int local = it * 1024 + tid * 4;        // 0..16383
            f32x4 v = *reinterpret_cast<const f32x4*>(B1 + base + local);
            #pragma unroll
            for (int q = 0; q < 4; ++q) {
                if (v[q] != 0.0f) {
                    uint32_t p = atomicAdd(&rcur, 1u);       // LDS atomic only
                    if (p < RCAP) hits[p] = (uint32_t)(local + q);
                }
            }
        }
        __syncthreads();
        uint32_t cnt = rcur;
        uint32_t cl = cnt > RCAP ? RCAP : cnt;
        if ((uint32_t)tid < cl) {
            uint32_t j = hits[tid];
            csr_col[(uint32_t)i * RCAP + tid] = j;
            uint32_t qq = atomicAdd(&col_cnt[j], 1u);        // one batched drain per row
            if (qq < CCAP) csc_row[j * CCAP + qq] = (uint32_t)i;
        }
        if (tid == 0) row_cnt[i] = cnt;            // true count (clamp at use sites)
    } else {
        int c = tid & 63, rr = tid >> 6;
        for (int k = tid * 4; k < 4096; k += 1024)
            *reinterpret_cast<f32x4*>(wsm + k) =
                *reinterpret_cast<const f32x4*>(W0 + k);
        int row0 = (blockIdx.x - NN) * 4;
        xs[rr][c] = x0[(row0 + rr) * 64 + c];
        __syncthreads();
        float acc = 0.f;
        #pragma unroll
        for (int k = 0; k < 64; ++k) acc = fmaf(xs[rr][k], wsm[k * 64 + c], acc);
        y0[(row0 + rr) * 64 + c] = acc;
    }
}

// K_B: one wave per node row. rscale[i] = nnorm[i]/sum_{j in row} enorm[j];
// scales y0 row in place so the edge gather is a pure sum.
__global__ __launch_bounds__(256) void k_rowscale(
        const uint32_t* __restrict__ row_cnt, const uint32_t* __restrict__ col_cnt,
        const uint32_t* __restrict__ csr_col,
        float* __restrict__ rowscale, float* __restrict__ y0) {
    int i = blockIdx.x * 4 + (threadIdx.x >> 6);
    int lane = threadIdx.x & 63;
    uint32_t c = row_cnt[i];
    uint32_t cl = c > RCAP ? RCAP : c;
    const uint32_t* p = csr_col + (uint32_t)i * RCAP;
    float s = 0.f;
    for (uint32_t t = lane; t < cl; t += 64) {
        float cj = (float)col_cnt[p[t]];
        s += 1.0f / (cj * sqrtf(cj));
    }
    #pragma unroll
    for (int off = 32; off >= 1; off >>= 1) s += __shfl_xor(s, off);
    float rs = 1.0f / (sqrtf((float)c) * s);
    y0[i * 64 + lane] *= rs;
    if (lane == 0) rowscale[i] = rs;
}

// K_C: per edge j (4/block): gather x1row = sum_{i in col j} y0s[i,:] with
// prefetched indices (u0/u1) + wave-uniform trip count. On-the-fly colscale
// (fl==0 lanes accumulate 1/sqrt(row_cnt)), relu->out1, then block 64x64 GEMM:
// z1s = colscale*(x1@W1).
__global__ __launch_bounds__(256) void k_edge_fused(
        const uint32_t* __restrict__ col_cnt, const uint32_t* __restrict__ csc_row,
        const uint32_t* __restrict__ row_cnt, const float* __restrict__ y0s,
        const float* __restrict__ bias01, const float* __restrict__ W1,
        float* __restrict__ z1s, float* __restrict__ out1) {
    __shared__ float w1s[64 * 64];
    __shared__ float xrow[4][64];
    __shared__ float csh[4];
    int tid = threadIdx.x;
    for (int k = tid * 4; k < 4096; k += 1024)
        *reinterpret_cast<f32x4*>(w1s + k) =
            *reinterpret_cast<const f32x4*>(W1 + k);
    int w = tid >> 6, lane = tid & 63;
    int j = blockIdx.x * 4 + w;
    uint32_t c = col_cnt[j];
    uint32_t e = c > CCAP ? CCAP : c;
    const uint32_t* p = csc_row + (uint32_t)j * CCAP;
    uint32_t u0 = p[lane];                  // indices 0..63 (tail lanes: unused garbage)
    uint32_t u1 = p[64 + lane];             // indices 64..95 (lanes >=32 unused)
    int g = lane >> 4, fl = lane & 15;
    float4 acc = make_float4(0.f, 0.f, 0.f, 0.f);
    float ns = 0.f;
    uint32_t niter = (e + 3u) >> 2;         // uniform across the wave
    for (uint32_t k = 0; k < niter; ++k) {
        uint32_t t = g + 4u * k;
        uint32_t idx = (t < 64u) ? (uint32_t)__shfl((int)u0, (int)t)
                                 : (uint32_t)__shfl((int)u1, (int)(t - 64u));
        if (t < e) {
            const float4 v = *reinterpret_cast<const float4*>(y0s + idx * 64u + fl * 4);
            if (fl == 0) ns += 1.0f / sqrtf((float)row_cnt[idx]);
            acc.x += v.x; acc.y += v.y; acc.z += v.z; acc.w += v.w;
        }
    }
    acc.x += __shfl_xor(acc.x, 16); acc.y += __shfl_xor(acc.y, 16);
    acc.z += __shfl_xor(acc.z, 16); acc.w += __shfl_xor(acc.w, 16);
    acc.x += __shfl_xor(acc.x, 32); acc.y += __shfl_xor(acc.y, 32);
    acc.z += __shfl_xor(acc.z, 32); acc.w += __shfl_xor(acc.w, 32);
    ns += __shfl_xor(ns, 16); ns += __shfl_xor(ns, 32);
    float cf = (float)c;
    float cs = __shfl(1.0f / (cf * sqrtf(cf) * ns), 0);   // colscale[j], broadcast
    if (g == 0) {
        const float4 bb = *reinterpret_cast<const float4*>(bias01 + fl * 4);
        float4 val = make_float4(fmaf(cs, acc.x, bb.x), fmaf(cs, acc.y, bb.y),
                                 fmaf(cs, acc.z, bb.z), fmaf(cs, acc.w, bb.w));
        *reinterpret_cast<float4*>(&xrow[w][fl * 4]) = val;
        float4 r = make_float4(fmaxf(val.x, 0.f), fmaxf(val.y, 0.f),
                               fmaxf(val.z, 0.f), fmaxf(val.w, 0.f));
        *reinterpret_cast<float4*>(out1 + j * 64u + fl * 4) = r;
        if (fl == 0) csh[w] = cs;
    }
    __syncthreads();
    float z = 0.f;
    #pragma unroll
    for (int k = 0; k < 64; ++k) z = fmaf(xrow[w][k], w1s[k * 64 + lane], z);
    z1s[j * 64 + lane] = csh[w] * z;
}

// K_D: out0[i,:] = relu(rowscale[i] * sum_{j in row i} z1s[j,:] + b10)
__global__ __launch_bounds__(256) void k_node_gather(
        const uint32_t* __restrict__ row_cnt, const uint32_t* __restrict__ csr_col,
        const float* __restrict__ rowscale, const float* __restrict__ z1s,
        const float* __restrict__ bias10, float* __restrict__ out0) {
    int w = threadIdx.x >> 6, lane = threadIdx.x & 63;
    int i = blockIdx.x * 4 + w;
    uint32_t c = row_cnt[i];
    uint32_t e = c > RCAP ? RCAP : c;
    const uint32_t* p = csr_col + (uint32_t)i * RCAP;
    uint32_t u0 = p[lane];
    uint32_t u1 = p[64 + lane];
    int g = lane >> 4, fl = lane & 15;
    float4 acc = make_float4(0.f, 0.f, 0.f, 0.f);
    uint32_t niter = (e + 3u) >> 2;         // uniform across the wave
    for (uint32_t k = 0; k < niter; ++k) {
        uint32_t t = g + 4u * k;
        uint32_t idx = (t < 64u) ? (uint32_t)__shfl((int)u0, (int)t)
                                 : (uint32_t)__shfl((int)u1, (int)(t - 64u));
        if (t < e) {
            const float4 v = *reinterpret_cast<const float4*>(z1s + idx * 64u + fl * 4);
            acc.x += v.x; acc.y += v.y; acc.z += v.z; acc.w += v.w;
        }
    }
    acc.x += __shfl_xor(acc.x, 16); acc.y += __shfl_xor(acc.y, 16);
    acc.z += __shfl_xor(acc.z, 16); acc.w += __shfl_xor(acc.w, 16);
    acc.x += __shfl_xor(acc.x, 32); acc.y += __shfl_xor(acc.y, 32);
    acc.z += __shfl_xor(acc.z, 32); acc.w += __shfl_xor(acc.w, 32);
    if (g == 0) {
        float rs = rowscale[i];
        const float4 bb = *reinterpret_cast<const float4*>(bias10 + fl * 4);
        float4 r = make_float4(fmaxf(fmaf(rs, acc.x, bb.x), 0.f),
                               fmaxf(fmaf(rs, acc.y, bb.y), 0.f),
                               fmaxf(fmaf(rs, acc.z, bb.z), 0.f),
                               fmaxf(fmaf(rs, acc.w, bb.w), 0.f));
        *reinterpret_cast<float4*>(out0 + i * 64u + fl * 4) = r;
    }
}

extern "C" void kernel_launch(void* const* d_in, const int* in_sizes, int n_in,
                              void* d_out, int out_size, void* d_ws, size_t ws_size,
                              hipStream_t stream) {
    const float* x0  = (const float*)d_in[0];
    const float* B1  = (const float*)d_in[1];
    const float* W0  = (const float*)d_in[2];
    const float* W1  = (const float*)d_in[3];
    const float* b01 = (const float*)d_in[4];
    const float* b10 = (const float*)d_in[5];
    float* out = (float*)d_out;
    char* ws = (char*)d_ws;

    uint32_t* col_cnt = (uint32_t*)(ws + OFF_COLCNT);
    uint32_t* row_cnt = (uint32_t*)(ws + OFF_ROWCNT);
    float*    rscale  = (float*)(ws + OFF_RSCALE);
    uint32_t* csr_col = (uint32_t*)(ws + OFF_CSR);
    uint32_t* csc_row = (uint32_t*)(ws + OFF_CSC);
    float*    y0      = (float*)(ws + OFF_Y0);
    float*    z1      = (float*)(ws + OFF_Z1);

    hipMemsetAsync(col_cnt, 0, MEMSET_BYTES, stream);

    k_scan_gemm<<<NN + NN / 4, 256, 0, stream>>>(B1, x0, W0, row_cnt, col_cnt,
            csr_col, csc_row, y0);
    k_rowscale<<<NN / 4, 256, 0, stream>>>(row_cnt, col_cnt, csr_col, rscale, y0);
    k_edge_fused<<<NE / 4, 256, 0, stream>>>(col_cnt, csc_row, row_cnt, y0,
            b01, W1, z1, out + NN * 64);
    k_node_gather<<<NN / 4, 256, 0, stream>>>(row_cnt, csr_col, rscale, z1, b10, out);
}